// Round 3
// baseline (205.195 us; speedup 1.0000x reference)
//
#include <hip/hip_runtime.h>

#define B_ 8
#define C_ 64
#define OUT_ 64
#define KS_ 16
#define NS_ 4096
#define K_ 32
#define DIM_ 3
#define G_ 8   // support points (n) per block

__global__ __launch_bounds__(256) void convpoint_kernel(
    const float* __restrict__ input,      // (B,C,NS,K)
    const float* __restrict__ points,     // (B,DIM,NS,K)
    const float* __restrict__ support,    // (B,DIM,NS)
    const float* __restrict__ weight,     // (C*KS, OUT)
    const float* __restrict__ bias,       // (OUT)
    const float* __restrict__ centers,    // (DIM,KS)
    const float* __restrict__ W1, const float* __restrict__ b1,
    const float* __restrict__ W2, const float* __restrict__ b2,
    const float* __restrict__ W3, const float* __restrict__ b3,
    float* __restrict__ out0,             // (B,OUT,NS)
    float* __restrict__ out1)             // (B,DIM,NS)
{
    __shared__ float s_W1[KS_*48];
    __shared__ float s_b1[KS_];
    __shared__ float s_W2[KS_*KS_];
    __shared__ float s_b2[KS_];
    __shared__ float s_W3[KS_*KS_];
    __shared__ float s_b3[KS_];
    __shared__ float s_cent[48];
    __shared__ float s_mat[G_][KS_][K_];   // [g][m][k]  16 KB
    __shared__ float s_F[G_][C_*KS_];      // j' = m*64 + c  32 KB
    __shared__ float s_part[4][G_][OUT_];  // per-wave partials  8 KB

    const int tid = threadIdx.x;
    const int bidx = blockIdx.x;
    const int b = bidx / (NS_/G_);
    const int grp = bidx % (NS_/G_);
    const int n0 = grp * G_;

    // stage tiny MLP params into LDS
    for (int i = tid; i < KS_*48; i += 256) s_W1[i] = W1[i];
    for (int i = tid; i < KS_*KS_; i += 256) { s_W2[i] = W2[i]; s_W3[i] = W3[i]; }
    if (tid < KS_) { s_b1[tid] = b1[tid]; s_b2[tid] = b2[tid]; s_b3[tid] = b3[tid]; }
    if (tid < 48) s_cent[tid] = centers[tid];
    __syncthreads();

    const int wave = tid >> 6;
    const int lane = tid & 63;
    const int half = lane >> 5;
    const int k = lane & 31;

    // ---- Phase A+B: radius normalize + 3-layer MLP -> s_mat[g][m][k] ----
    // wave w: lanes 0-31 -> g=2w, lanes 32-63 -> g=2w+1; lane's k = lane&31
    {
        const int g = 2*wave + half;
        const int n = n0 + g;
        float p[3];
        float r2 = 0.f;
        #pragma unroll
        for (int d = 0; d < 3; ++d) {
            float pv = points[((b*3 + d)*NS_ + n)*K_ + k];
            float sv = support[(b*3 + d)*NS_ + n];
            p[d] = pv - sv;
            r2 += p[d]*p[d];
        }
        #pragma unroll
        for (int m = 1; m < 32; m <<= 1)
            r2 = fmaxf(r2, __shfl_xor(r2, m, 64));
        float maxi = sqrtf(r2);
        if (maxi == 0.f) maxi = 1.f;
        float inv = 1.f / maxi;

        float rel[48];
        #pragma unroll
        for (int d = 0; d < 3; ++d) {
            float pn = p[d]*inv;
            #pragma unroll
            for (int s = 0; s < 16; ++s)
                rel[d*16+s] = pn - s_cent[d*16+s];
        }
        float h1[16], h2[16];
        #pragma unroll
        for (int i = 0; i < 16; ++i) {
            float acc = s_b1[i];
            #pragma unroll
            for (int j = 0; j < 48; ++j)
                acc += rel[j]*s_W1[i*48+j];
            h1[i] = fmaxf(acc, 0.f);
        }
        #pragma unroll
        for (int i = 0; i < 16; ++i) {
            float acc = s_b2[i];
            #pragma unroll
            for (int j = 0; j < 16; ++j) acc += h1[j]*s_W2[i*16+j];
            h2[i] = fmaxf(acc, 0.f);
        }
        #pragma unroll
        for (int i = 0; i < 16; ++i) {
            float acc = s_b3[i];
            #pragma unroll
            for (int j = 0; j < 16; ++j) acc += h2[j]*s_W3[i*16+j];
            s_mat[g][i][k] = fmaxf(acc, 0.f);   // [m][k]: contiguous across k-lanes
        }
    }
    __syncthreads();

    // ---- Phase C: F[m*64+c] = sum_k input[b,c,n,k]*mat[m][k] ----
    // wave w handles its 2 n's; lane = channel c
    {
        const int c = lane;
        #pragma unroll
        for (int gi = 0; gi < 2; ++gi) {
            const int g = 2*wave + gi;
            const int n = n0 + g;
            const float* inp = input + ((size_t)(b*C_ + c)*NS_ + n)*K_;
            float in[32];
            #pragma unroll
            for (int q = 0; q < 8; ++q) {
                float4 v = ((const float4*)inp)[q];
                in[q*4+0]=v.x; in[q*4+1]=v.y; in[q*4+2]=v.z; in[q*4+3]=v.w;
            }
            #pragma unroll
            for (int m = 0; m < 16; ++m) {
                float acc = 0.f;
                #pragma unroll
                for (int kq = 0; kq < 8; ++kq) {
                    float4 mv = *(const float4*)&s_mat[g][m][kq*4];  // broadcast, conflict-free
                    acc += in[kq*4+0]*mv.x + in[kq*4+1]*mv.y
                         + in[kq*4+2]*mv.z + in[kq*4+3]*mv.w;
                }
                s_F[g][m*64 + c] = acc;   // contiguous across lanes
            }
        }
    }
    __syncthreads();

    // ---- Phase D: out[g][o] = (sum_j' F[j']*weight[row(j')][o])/K + bias[o] ----
    // wave w owns j' in [256w, 256w+256); lane: oq=lane&15 -> o=4*oq..+3, jc=lane>>4
    {
        const int oq = lane & 15;
        const int jc = lane >> 4;
        float acc[8][4];
        #pragma unroll
        for (int g = 0; g < 8; ++g)
            #pragma unroll
            for (int q = 0; q < 4; ++q) acc[g][q] = 0.f;

        #pragma unroll 2
        for (int it = 0; it < 16; ++it) {
            const int j0 = wave*256 + it*16 + 4*jc;
            float4 f[8];
            #pragma unroll
            for (int g = 0; g < 8; ++g)
                f[g] = *(const float4*)&s_F[g][j0];
            #pragma unroll
            for (int q = 0; q < 4; ++q) {
                const int jp = j0 + q;
                const int r = ((jp & 63) << 4) | (jp >> 6);   // row = c*16+m
                float4 wv = *(const float4*)&weight[r*64 + 4*oq];
                #pragma unroll
                for (int g = 0; g < 8; ++g) {
                    const float fv = (&f[g].x)[q];
                    acc[g][0] += fv*wv.x;
                    acc[g][1] += fv*wv.y;
                    acc[g][2] += fv*wv.z;
                    acc[g][3] += fv*wv.w;
                }
            }
        }

        // reduce across jc (lanes xor 16, 32)
        #pragma unroll
        for (int g = 0; g < 8; ++g) {
            #pragma unroll
            for (int q = 0; q < 4; ++q) {
                float v = acc[g][q];
                v += __shfl_xor(v, 16, 64);
                v += __shfl_xor(v, 32, 64);
                acc[g][q] = v;
            }
        }
        if (lane < 16) {
            #pragma unroll
            for (int g = 0; g < 8; ++g)
                *(float4*)&s_part[wave][g][4*oq] =
                    make_float4(acc[g][0], acc[g][1], acc[g][2], acc[g][3]);
        }
    }
    __syncthreads();

    // ---- final cross-wave reduce + writeback ----
    {
        const int o = tid & 63;
        const int gg = tid >> 6;
        const float bo = bias[o];
        #pragma unroll
        for (int gi = 0; gi < 2; ++gi) {
            const int g = gg + 4*gi;
            float s = s_part[0][g][o] + s_part[1][g][o]
                    + s_part[2][g][o] + s_part[3][g][o];
            out0[(size_t)(b*OUT_ + o)*NS_ + n0 + g] = s*(1.f/32.f) + bo;
        }
    }

    // ---- output 1: pass-through support_points ----
    if (tid < 3*G_) {
        int d = tid / G_, gg2 = tid % G_;
        int idx = (b*3 + d)*NS_ + n0 + gg2;
        out1[idx] = support[idx];
    }
}

extern "C" void kernel_launch(void* const* d_in, const int* in_sizes, int n_in,
                              void* d_out, int out_size, void* d_ws, size_t ws_size,
                              hipStream_t stream) {
    const float* input   = (const float*)d_in[0];
    const float* points  = (const float*)d_in[1];
    const float* support = (const float*)d_in[2];
    const float* weight  = (const float*)d_in[3];
    const float* bias    = (const float*)d_in[4];
    const float* centers = (const float*)d_in[5];
    const float* W1 = (const float*)d_in[6];
    const float* b1 = (const float*)d_in[7];
    const float* W2 = (const float*)d_in[8];
    const float* b2 = (const float*)d_in[9];
    const float* W3 = (const float*)d_in[10];
    const float* b3 = (const float*)d_in[11];

    float* out0 = (float*)d_out;
    float* out1 = out0 + (size_t)B_*OUT_*NS_;

    dim3 grid(B_ * (NS_/G_));
    convpoint_kernel<<<grid, 256, 0, stream>>>(
        input, points, support, weight, bias, centers,
        W1, b1, W2, b2, W3, b3, out0, out1);
}